// Round 9
// baseline (252.298 us; speedup 1.0000x reference)
//
#include <hip/hip_runtime.h>

#define Bb 32
#define Nn 512
#define Dd 256
#define KC 1792   // 256 (self) + 6*256 (edge types)
#define NR (Bb * Nn)   // 16384 rows

typedef __bf16 bf16x8 __attribute__((ext_vector_type(8)));
typedef float  f32x4  __attribute__((ext_vector_type(4)));
typedef int    i32x4  __attribute__((ext_vector_type(4)));
typedef unsigned short u16;

__device__ __forceinline__ u16 f2bf(float x){
  union { float f; unsigned u; } c; c.f = x;
  unsigned u = c.u;
  u += 0x7FFFu + ((u >> 16) & 1u);   // RNE
  return (u16)(u >> 16);
}

// ---------------- K0: WcatT[e][c] = Wcat[c][e] in bf16, [256 x 1792] -------
__global__ __launch_bounds__(256) void k_prep(
    const float* __restrict__ wself,
    const float* __restrict__ w0, const float* __restrict__ w1,
    const float* __restrict__ w2, const float* __restrict__ w3,
    const float* __restrict__ w4, const float* __restrict__ w5,
    u16* __restrict__ wcatT){
  int e = blockIdx.x;
  const float* Ws[7] = {wself, w0, w1, w2, w3, w4, w5};
  for (int c = threadIdx.x; c < KC; c += 256){
    int g = c >> 8, j = c & 255;
    wcatT[(size_t)e*KC + c] = f2bf(Ws[g][j*Dd + e]);
  }
}

// ---------------- K0b: pack node_mask into bit-words, Mp[b][w] ------------
__global__ __launch_bounds__(512) void k_mask(
    const int* __restrict__ mask, unsigned* __restrict__ Mp){
  int t = threadIdx.x;                 // 512 = 32 batches x 16 words
  int b = t >> 4, w = t & 15;
  const int4* mp = (const int4*)(mask + (size_t)b * Nn + w * 32);
  unsigned v = 0;
  #pragma unroll
  for (int j = 0; j < 8; ++j){
    int4 x = mp[j];
    v |= ((unsigned)x.x << (j * 4)) | ((unsigned)x.y << (j * 4 + 1)) |
         ((unsigned)x.z << (j * 4 + 2)) | ((unsigned)x.w << (j * 4 + 3));
  }
  Mp[t] = v;
}

// ---------------- K1: bitpack graphs (occupancy-first streaming) -----------
// Thread = (graph g, row r, word w). Grid 6144 blocks -> ~96 waves/CU issued,
// 32 resident: 32 KB of 1KB-loads in flight per CU covers HBM latency (m13
// recipe). 8 contiguous int4 loads, bit-op pack, popc + 16-lane reduce ->
// per-(g,row) partial counts pc (no atomics). Gp layout unchanged.
__global__ __launch_bounds__(256) void k_pack(
    const int* __restrict__ g0, const int* __restrict__ g1,
    const int* __restrict__ g2, const int* __restrict__ g3,
    const int* __restrict__ g4, const int* __restrict__ g5,
    const unsigned* __restrict__ Mp,
    unsigned* __restrict__ Gp, int* __restrict__ pc){
  int blk = blockIdx.x;
  int gsel = blk >> 10, rblk = blk & 1023;
  int tid = threadIdx.x;
  int w = tid & 15, r = rblk * 16 + (tid >> 4);   // r in [0, 16384)
  int bb = r >> 9, m = r & 511;

  const int* gp = g0;                  // block-uniform branchless select
  gp = (gsel == 1) ? g1 : gp;  gp = (gsel == 2) ? g2 : gp;
  gp = (gsel == 3) ? g3 : gp;  gp = (gsel == 4) ? g4 : gp;
  gp = (gsel == 5) ? g5 : gp;

  unsigned keep = Mp[bb * 16 + w] & ~(((m >> 5) == w) ? (1u << (m & 31)) : 0u);
  const i32x4* p = (const i32x4*)(gp + (size_t)r * Nn + w * 32);
  i32x4 x[8];
  #pragma unroll
  for (int j = 0; j < 8; ++j) x[j] = p[j];
  unsigned v = 0;
  #pragma unroll
  for (int j = 0; j < 8; ++j){
    v |= ((unsigned)x[j][0] << (4 * j))     | ((unsigned)x[j][1] << (4 * j + 1)) |
         ((unsigned)x[j][2] << (4 * j + 2)) | ((unsigned)x[j][3] << (4 * j + 3));
  }
  v &= keep;
  Gp[((size_t)gsel * NR + r) * 16 + w] = v;
  int s = __popc(v);
  s += __shfl_xor(s, 1); s += __shfl_xor(s, 2);
  s += __shfl_xor(s, 4); s += __shfl_xor(s, 8);
  if (w == 0) pc[gsel * NR + r] = s;
}

// ---------------- K1b: rs[r] = mask ? 1/max(nn,1) : 0 ---------------------
__global__ __launch_bounds__(256) void k_rs(
    const int* __restrict__ pc, const int* __restrict__ mask,
    float* __restrict__ rs){
  int r = blockIdx.x * 256 + threadIdx.x;
  int s = 0;
  #pragma unroll
  for (int g = 0; g < 6; ++g) s += pc[g * NR + r];
  rs[r] = mask[r] ? 1.0f / (float)(s < 1 ? 1 : s) : 0.0f;
}

// ---------------- K2: dw (sigmoid), Z node copy (bf16), X'^T build ---------
__global__ __launch_bounds__(256) void k_dw(
    const float* __restrict__ node, const int* __restrict__ mask,
    const float* __restrict__ wnw, const float* __restrict__ bnw,
    float* __restrict__ aw_out,    // already offset by t*N
    u16* __restrict__ Z, u16* __restrict__ XT){
  __shared__ float tile[32][268];
  __shared__ float dws[32];
  int b = blockIdx.x >> 4, n0 = (blockIdx.x & 15) << 5;
  int t = threadIdx.x;
  int row = t >> 3, seg = t & 7;
  const float* src = node + ((size_t)(b * Nn + n0 + row)) * Dd + seg * 32;
  u16* zn = Z + ((size_t)(b * Nn + n0 + row)) * KC + seg * 32;
  #pragma unroll
  for (int c = 0; c < 8; ++c){
    float4 v = ((const float4*)src)[c];
    tile[row][seg * 32 + c * 4 + 0] = v.x;
    tile[row][seg * 32 + c * 4 + 1] = v.y;
    tile[row][seg * 32 + c * 4 + 2] = v.z;
    tile[row][seg * 32 + c * 4 + 3] = v.w;
    ushort4 h;
    h.x = f2bf(v.x); h.y = f2bf(v.y); h.z = f2bf(v.z); h.w = f2bf(v.w);
    ((ushort4*)zn)[c] = h;
  }
  __syncthreads();
  float s = 0.f;
  #pragma unroll
  for (int c = 0; c < 32; ++c) s += tile[row][seg * 32 + c] * wnw[seg * 32 + c];
  s += __shfl_xor(s, 1); s += __shfl_xor(s, 2); s += __shfl_xor(s, 4);
  if (seg == 0){
    float dw = 1.f / (1.f + expf(-(s + bnw[0])));
    aw_out[b * (2 * Nn) + n0 + row] = dw;
    dws[row] = mask[b * Nn + n0 + row] ? dw : 0.f;
  }
  __syncthreads();
  #pragma unroll
  for (int p = 0; p < 4; ++p){
    int d = p * 64 + (t >> 2);
    int j0 = (t & 3) * 8;
    union { u16 h[8]; uint4 v; } pk;
    #pragma unroll
    for (int jj = 0; jj < 8; ++jj)
      pk.h[jj] = f2bf(dws[j0 + jj] * tile[j0 + jj][d]);
    *(uint4*)(XT + ((size_t)(b * Dd + d)) * Nn + n0 + j0) = pk.v;
  }
}

// ---------------- K3: aggregation GEMM  H'_k = rs * (G_k @ X') ------------
// grid (8, 32, 6): mtile, b, edge-type.  BM=64, BN=256(full D), BK=64, 4 waves
__global__ __launch_bounds__(256) void k_agg(
    const unsigned* __restrict__ Gp,
    const u16* __restrict__ XT, const float* __restrict__ rs,
    u16* __restrict__ Z){
  int mt = blockIdx.x, b = blockIdx.y, kg = blockIdx.z;
  int m0 = mt * 64;
  const unsigned* Gr = Gp + ((size_t)kg * Bb * Nn + b * Nn + m0) * 16;
  const u16* Xb = XT + (size_t)b * Dd * Nn;
  __shared__ u16 As[64 * 72];
  __shared__ u16 Bs[256 * 72];
  int t = threadIdx.x, lane = t & 63, wn = t >> 6;
  int arow = t >> 2, aq = t & 3;
  // preload this thread's 8 packed words (one per K-step), L2-hit
  unsigned wpre[8];
  #pragma unroll
  for (int ks = 0; ks < 8; ++ks)
    wpre[ks] = Gr[arow * 16 + ks * 2 + (aq >> 1)];

  f32x4 acc[4][4];
  #pragma unroll
  for (int i = 0; i < 4; ++i)
    #pragma unroll
    for (int q = 0; q < 4; ++q) acc[i][q] = (f32x4){0.f, 0.f, 0.f, 0.f};

  for (int ks = 0; ks < 8; ++ks){
    int k0 = ks * 64;
    { // A stage: unpack 16 bits -> bf16 0/1
      unsigned bits = (wpre[ks] >> ((aq & 1) * 16)) & 0xFFFFu;
      union { u16 h[16]; uint4 v[2]; } pk;
      #pragma unroll
      for (int c = 0; c < 16; ++c)
        pk.h[c] = ((bits >> c) & 1u) ? 0x3F80 : 0;
      *(uint4*)&As[arow * 72 + aq * 16]     = pk.v[0];
      *(uint4*)&As[arow * 72 + aq * 16 + 8] = pk.v[1];
    }
    // B stage: 256 rows (d) x 64 cols (n-slice) from X'^T
    #pragma unroll
    for (int p = 0; p < 8; ++p){
      int rowb = p * 32 + (t >> 3);
      *(uint4*)&Bs[rowb * 72 + (t & 7) * 8] =
          *(const uint4*)(Xb + (size_t)rowb * Nn + k0 + (t & 7) * 8);
    }
    __syncthreads();
    #pragma unroll
    for (int kk = 0; kk < 2; ++kk){
      bf16x8 av[4], bv[4];
      #pragma unroll
      for (int i = 0; i < 4; ++i)
        av[i] = *(const bf16x8*)&As[(i * 16 + (lane & 15)) * 72 + kk * 32 + (lane >> 4) * 8];
      #pragma unroll
      for (int q = 0; q < 4; ++q)
        bv[q] = *(const bf16x8*)&Bs[(wn * 64 + q * 16 + (lane & 15)) * 72 + kk * 32 + (lane >> 4) * 8];
      #pragma unroll
      for (int i = 0; i < 4; ++i)
        #pragma unroll
        for (int q = 0; q < 4; ++q)
          acc[i][q] = __builtin_amdgcn_mfma_f32_16x16x32_bf16(av[i], bv[q], acc[i][q], 0, 0, 0);
    }
    __syncthreads();
  }
  int kgcol = 256 + kg * 256 + wn * 64;
  #pragma unroll
  for (int i = 0; i < 4; ++i){
    #pragma unroll
    for (int r = 0; r < 4; ++r){
      int mg = m0 + i * 16 + (lane >> 4) * 4 + r;
      float sc = rs[b * Nn + mg];
      u16* zp = Z + ((size_t)(b * Nn + mg)) * KC + kgcol + (lane & 15);
      #pragma unroll
      for (int q = 0; q < 4; ++q)
        zp[q * 16] = f2bf(acc[i][q][r] * sc);
    }
  }
}

// ---------------- K4: update GEMM  out = relu(Z @ Wcat + b_self) ----------
// grid (2, 128): ntile, mtile. BM=128, BN=128, BK=64, 4 waves (2x2)
__global__ __launch_bounds__(256) void k_upd(
    const u16* __restrict__ Z, const u16* __restrict__ wcatT,
    const float* __restrict__ bself, float* __restrict__ outp){
  int n0 = blockIdx.x * 128, m0 = blockIdx.y * 128;
  __shared__ u16 As[128 * 72];
  __shared__ u16 Bs[128 * 72];
  int t = threadIdx.x, lane = t & 63, wid = t >> 6;
  int wm = wid >> 1, wn = wid & 1;
  f32x4 acc[4][4];
  #pragma unroll
  for (int i = 0; i < 4; ++i)
    #pragma unroll
    for (int q = 0; q < 4; ++q) acc[i][q] = (f32x4){0.f, 0.f, 0.f, 0.f};

  for (int ks = 0; ks < 28; ++ks){
    int k0 = ks * 64;
    #pragma unroll
    for (int p = 0; p < 4; ++p){
      int row = p * 32 + (t >> 3);
      *(uint4*)&As[row * 72 + (t & 7) * 8] =
          *(const uint4*)(Z + ((size_t)(m0 + row)) * KC + k0 + (t & 7) * 8);
      *(uint4*)&Bs[row * 72 + (t & 7) * 8] =
          *(const uint4*)(wcatT + ((size_t)(n0 + row)) * KC + k0 + (t & 7) * 8);
    }
    __syncthreads();
    #pragma unroll
    for (int kk = 0; kk < 2; ++kk){
      bf16x8 av[4], bv[4];
      #pragma unroll
      for (int i = 0; i < 4; ++i)
        av[i] = *(const bf16x8*)&As[(wm * 64 + i * 16 + (lane & 15)) * 72 + kk * 32 + (lane >> 4) * 8];
      #pragma unroll
      for (int q = 0; q < 4; ++q)
        bv[q] = *(const bf16x8*)&Bs[(wn * 64 + q * 16 + (lane & 15)) * 72 + kk * 32 + (lane >> 4) * 8];
      #pragma unroll
      for (int i = 0; i < 4; ++i)
        #pragma unroll
        for (int q = 0; q < 4; ++q)
          acc[i][q] = __builtin_amdgcn_mfma_f32_16x16x32_bf16(av[i], bv[q], acc[i][q], 0, 0, 0);
    }
    __syncthreads();
  }
  #pragma unroll
  for (int i = 0; i < 4; ++i){
    #pragma unroll
    for (int r = 0; r < 4; ++r){
      int mg = m0 + wm * 64 + i * 16 + (lane >> 4) * 4 + r;
      #pragma unroll
      for (int q = 0; q < 4; ++q){
        int e = n0 + wn * 64 + q * 16 + (lane & 15);
        float v = acc[i][q][r] + bself[e];
        outp[(size_t)mg * Dd + e] = v > 0.f ? v : 0.f;
      }
    }
  }
}

extern "C" void kernel_launch(void* const* d_in, const int* in_sizes, int n_in,
                              void* d_out, int out_size, void* d_ws, size_t ws_size,
                              hipStream_t stream){
  (void)in_sizes; (void)n_in; (void)out_size; (void)ws_size;
  const float* node  = (const float*)d_in[0];
  const int*   mask  = (const int*)d_in[1];
  const int*   g[6];
  for (int i = 0; i < 6; ++i) g[i] = (const int*)d_in[2 + i];
  const float* wnw   = (const float*)d_in[8];
  const float* bnw   = (const float*)d_in[9];
  const float* wself = (const float*)d_in[10];
  const float* bself = (const float*)d_in[11];
  const float* W[6];
  for (int i = 0; i < 6; ++i) W[i] = (const float*)d_in[12 + i];

  float* out_node = (float*)d_out;
  float* out_aw   = out_node + (size_t)Bb * Nn * Dd;

  char* ws = (char*)d_ws;
  u16*      wcatT = (u16*)(ws);                    // 917,504 B
  float*    rs    = (float*)(ws + 917504);         // 65,536 B
  unsigned* Mp    = (unsigned*)(ws + 983040);      // 2,048 B
  unsigned* Gp    = (unsigned*)(ws + 1048576);     // 6,291,456 B
  u16*      XT    = (u16*)(ws + 7340032);          // 8,388,608 B
  u16*      Z     = (u16*)(ws + 15728640);         // 58,720,256 B
  int*      pc    = (int*)(ws + 74448896);         // 393,216 B -> ends ~71.4 MB

  k_prep<<<256, 256, 0, stream>>>(wself, W[0], W[1], W[2], W[3], W[4], W[5], wcatT);
  k_mask<<<1, 512, 0, stream>>>(mask, Mp);
  k_pack<<<6144, 256, 0, stream>>>(g[0], g[1], g[2], g[3], g[4], g[5], Mp, Gp, pc);
  k_rs<<<64, 256, 0, stream>>>(pc, mask, rs);

  for (int t = 0; t < 2; ++t){
    const float* nsrc = (t == 0) ? node : out_node;   // iter-1 result lives in d_out
    k_dw<<<512, 256, 0, stream>>>(nsrc, mask, wnw, bnw, out_aw + t * Nn, Z, XT);
    k_agg<<<dim3(8, 32, 6), 256, 0, stream>>>(Gp, XT, rs, Z);
    k_upd<<<dim3(2, 128), 256, 0, stream>>>(Z, wcatT, bself, out_node);
  }
}

// Round 10
// 245.608 us; speedup vs baseline: 1.0272x; 1.0272x over previous
//
#include <hip/hip_runtime.h>

#define Bb 32
#define Nn 512
#define Dd 256
#define KC 1792   // 256 (self) + 6*256 (edge types)
#define NR (Bb * Nn)   // 16384 rows

typedef __bf16 bf16x8 __attribute__((ext_vector_type(8)));
typedef float  f32x4  __attribute__((ext_vector_type(4)));
typedef int    i32x4  __attribute__((ext_vector_type(4)));
typedef unsigned short u16;

__device__ __forceinline__ u16 f2bf(float x){
  union { float f; unsigned u; } c; c.f = x;
  unsigned u = c.u;
  u += 0x7FFFu + ((u >> 16) & 1u);   // RNE
  return (u16)(u >> 16);
}

// ---------------- K0: WcatT[e][c] = Wcat[c][e] in bf16, [256 x 1792] -------
__global__ __launch_bounds__(256) void k_prep(
    const float* __restrict__ wself,
    const float* __restrict__ w0, const float* __restrict__ w1,
    const float* __restrict__ w2, const float* __restrict__ w3,
    const float* __restrict__ w4, const float* __restrict__ w5,
    u16* __restrict__ wcatT){
  int e = blockIdx.x;
  const float* Ws[7] = {wself, w0, w1, w2, w3, w4, w5};
  for (int c = threadIdx.x; c < KC; c += 256){
    int g = c >> 8, j = c & 255;
    wcatT[(size_t)e*KC + c] = f2bf(Ws[g][j*Dd + e]);
  }
}

// ---------------- K1: bitpack graphs + nn (coalesced + asm-forced MLP) -----
// One wave = one row r, all 6 graphs. Lane l owns cols 4l..4l+3 (half 0) and
// 256+4l..4l+3 (half 1): every load instruction is 64 lanes x 16 B CONTIGUOUS
// (1 KB/instr, no TA amplification). 14 loads (6 graphs x 2 halves + 2 mask)
// issued as one asm-volatile batch -> guaranteed in flight; one vmcnt(0).
// Pack via 3-step shuffle-OR butterfly (verified in R4). rs written directly.
// Gp[k][b][m][w]: bit j of word w = masked G value at col 32w+j (unchanged).
#define GLD(d, p, o) asm volatile("global_load_dwordx4 %0, %1, off offset:" #o \
                                  : "=v"(d) : "v"(p))

__global__ __launch_bounds__(256) void k_pack(
    const int* __restrict__ g0, const int* __restrict__ g1,
    const int* __restrict__ g2, const int* __restrict__ g3,
    const int* __restrict__ g4, const int* __restrict__ g5,
    const int* __restrict__ mask,
    unsigned* __restrict__ Gp, float* __restrict__ rs){
  int t = threadIdx.x, l = t & 63, wv = t >> 6;
  int r = blockIdx.x * 4 + wv;          // r = b*512 + m
  int b = r >> 9, m = r & 511;
  size_t off = (size_t)r * Nn + l * 4;
  const int* pm = mask + (size_t)b * Nn + l * 4;
  const int* pa = g0 + off; const int* pb = g1 + off; const int* pcx = g2 + off;
  const int* pd = g3 + off; const int* pe = g4 + off; const int* pf = g5 + off;

  i32x4 A0,A1,B0,B1,C0,C1,D0,D1,E0,E1,F0,F1,M0,M1;
  GLD(M0,pm,0);  GLD(M1,pm,1024);
  GLD(A0,pa,0);  GLD(A1,pa,1024);
  GLD(B0,pb,0);  GLD(B1,pb,1024);
  GLD(C0,pcx,0); GLD(C1,pcx,1024);
  GLD(D0,pd,0);  GLD(D1,pd,1024);
  GLD(E0,pe,0);  GLD(E1,pe,1024);
  GLD(F0,pf,0);  GLD(F1,pf,1024);
  asm volatile("s_waitcnt vmcnt(0)" ::: "memory");
  __builtin_amdgcn_sched_barrier(0);

  int s1 = (l & 1) * 4, s2 = ((l >> 1) & 1) * 8, s3 = ((l >> 2) & 1) * 16;
  unsigned dm0 = ((m >> 2) == l)      ? (1u << (m & 3)) : 0u;
  unsigned dm1 = ((m >> 2) == 64 + l) ? (1u << (m & 3)) : 0u;
  int stot = 0;
#define PK(G, MM, DM, k, h) {                                              \
    unsigned nib = (unsigned)((G[0] & MM[0]) | ((G[1] & MM[1]) << 1) |     \
                              ((G[2] & MM[2]) << 2) | ((G[3] & MM[3]) << 3)) \
                   & ~(DM);                                                \
    stot += __popc(nib);                                                   \
    unsigned v = nib << s1; v |= (unsigned)__shfl_xor((int)v, 1);          \
    v <<= s2;               v |= (unsigned)__shfl_xor((int)v, 2);          \
    v <<= s3;               v |= (unsigned)__shfl_xor((int)v, 4);          \
    if ((l & 7) == 0)                                                      \
      Gp[((size_t)(k) * NR + r) * 16 + (h) * 8 + (l >> 3)] = v; }
  PK(A0,M0,dm0,0,0) PK(A1,M1,dm1,0,1)
  PK(B0,M0,dm0,1,0) PK(B1,M1,dm1,1,1)
  PK(C0,M0,dm0,2,0) PK(C1,M1,dm1,2,1)
  PK(D0,M0,dm0,3,0) PK(D1,M1,dm1,3,1)
  PK(E0,M0,dm0,4,0) PK(E1,M1,dm1,4,1)
  PK(F0,M0,dm0,5,0) PK(F1,M1,dm1,5,1)
#undef PK
  #pragma unroll
  for (int o = 1; o < 64; o <<= 1) stot += __shfl_xor(stot, o);
  if (l == 0)
    rs[r] = mask[r] ? 1.0f / (float)(stot < 1 ? 1 : stot) : 0.0f;
}
#undef GLD

// ---------------- K2: dw (sigmoid), Z node copy (bf16), X'^T build ---------
__global__ __launch_bounds__(256) void k_dw(
    const float* __restrict__ node, const int* __restrict__ mask,
    const float* __restrict__ wnw, const float* __restrict__ bnw,
    float* __restrict__ aw_out,    // already offset by t*N
    u16* __restrict__ Z, u16* __restrict__ XT){
  __shared__ float tile[32][268];
  __shared__ float dws[32];
  int b = blockIdx.x >> 4, n0 = (blockIdx.x & 15) << 5;
  int t = threadIdx.x;
  int row = t >> 3, seg = t & 7;
  const float* src = node + ((size_t)(b * Nn + n0 + row)) * Dd + seg * 32;
  u16* zn = Z + ((size_t)(b * Nn + n0 + row)) * KC + seg * 32;
  #pragma unroll
  for (int c = 0; c < 8; ++c){
    float4 v = ((const float4*)src)[c];
    tile[row][seg * 32 + c * 4 + 0] = v.x;
    tile[row][seg * 32 + c * 4 + 1] = v.y;
    tile[row][seg * 32 + c * 4 + 2] = v.z;
    tile[row][seg * 32 + c * 4 + 3] = v.w;
    ushort4 h;
    h.x = f2bf(v.x); h.y = f2bf(v.y); h.z = f2bf(v.z); h.w = f2bf(v.w);
    ((ushort4*)zn)[c] = h;
  }
  __syncthreads();
  float s = 0.f;
  #pragma unroll
  for (int c = 0; c < 32; ++c) s += tile[row][seg * 32 + c] * wnw[seg * 32 + c];
  s += __shfl_xor(s, 1); s += __shfl_xor(s, 2); s += __shfl_xor(s, 4);
  if (seg == 0){
    float dw = 1.f / (1.f + expf(-(s + bnw[0])));
    aw_out[b * (2 * Nn) + n0 + row] = dw;
    dws[row] = mask[b * Nn + n0 + row] ? dw : 0.f;
  }
  __syncthreads();
  #pragma unroll
  for (int p = 0; p < 4; ++p){
    int d = p * 64 + (t >> 2);
    int j0 = (t & 3) * 8;
    union { u16 h[8]; uint4 v; } pk;
    #pragma unroll
    for (int jj = 0; jj < 8; ++jj)
      pk.h[jj] = f2bf(dws[j0 + jj] * tile[j0 + jj][d]);
    *(uint4*)(XT + ((size_t)(b * Dd + d)) * Nn + n0 + j0) = pk.v;
  }
}

// ---------------- K3: aggregation GEMM  H'_k = rs * (G_k @ X') ------------
// grid (8, 32, 6): mtile, b, edge-type.  BM=64, BN=256(full D), BK=64, 4 waves
__global__ __launch_bounds__(256) void k_agg(
    const unsigned* __restrict__ Gp,
    const u16* __restrict__ XT, const float* __restrict__ rs,
    u16* __restrict__ Z){
  int mt = blockIdx.x, b = blockIdx.y, kg = blockIdx.z;
  int m0 = mt * 64;
  const unsigned* Gr = Gp + ((size_t)kg * Bb * Nn + b * Nn + m0) * 16;
  const u16* Xb = XT + (size_t)b * Dd * Nn;
  __shared__ u16 As[64 * 72];
  __shared__ u16 Bs[256 * 72];
  int t = threadIdx.x, lane = t & 63, wn = t >> 6;
  int arow = t >> 2, aq = t & 3;
  // preload this thread's 8 packed words (one per K-step), L2-hit
  unsigned wpre[8];
  #pragma unroll
  for (int ks = 0; ks < 8; ++ks)
    wpre[ks] = Gr[arow * 16 + ks * 2 + (aq >> 1)];

  f32x4 acc[4][4];
  #pragma unroll
  for (int i = 0; i < 4; ++i)
    #pragma unroll
    for (int q = 0; q < 4; ++q) acc[i][q] = (f32x4){0.f, 0.f, 0.f, 0.f};

  for (int ks = 0; ks < 8; ++ks){
    int k0 = ks * 64;
    { // A stage: unpack 16 bits -> bf16 0/1
      unsigned bits = (wpre[ks] >> ((aq & 1) * 16)) & 0xFFFFu;
      union { u16 h[16]; uint4 v[2]; } pk;
      #pragma unroll
      for (int c = 0; c < 16; ++c)
        pk.h[c] = ((bits >> c) & 1u) ? 0x3F80 : 0;
      *(uint4*)&As[arow * 72 + aq * 16]     = pk.v[0];
      *(uint4*)&As[arow * 72 + aq * 16 + 8] = pk.v[1];
    }
    // B stage: 256 rows (d) x 64 cols (n-slice) from X'^T
    #pragma unroll
    for (int p = 0; p < 8; ++p){
      int rowb = p * 32 + (t >> 3);
      *(uint4*)&Bs[rowb * 72 + (t & 7) * 8] =
          *(const uint4*)(Xb + (size_t)rowb * Nn + k0 + (t & 7) * 8);
    }
    __syncthreads();
    #pragma unroll
    for (int kk = 0; kk < 2; ++kk){
      bf16x8 av[4], bv[4];
      #pragma unroll
      for (int i = 0; i < 4; ++i)
        av[i] = *(const bf16x8*)&As[(i * 16 + (lane & 15)) * 72 + kk * 32 + (lane >> 4) * 8];
      #pragma unroll
      for (int q = 0; q < 4; ++q)
        bv[q] = *(const bf16x8*)&Bs[(wn * 64 + q * 16 + (lane & 15)) * 72 + kk * 32 + (lane >> 4) * 8];
      #pragma unroll
      for (int i = 0; i < 4; ++i)
        #pragma unroll
        for (int q = 0; q < 4; ++q)
          acc[i][q] = __builtin_amdgcn_mfma_f32_16x16x32_bf16(av[i], bv[q], acc[i][q], 0, 0, 0);
    }
    __syncthreads();
  }
  int kgcol = 256 + kg * 256 + wn * 64;
  #pragma unroll
  for (int i = 0; i < 4; ++i){
    #pragma unroll
    for (int r = 0; r < 4; ++r){
      int mg = m0 + i * 16 + (lane >> 4) * 4 + r;
      float sc = rs[b * Nn + mg];
      u16* zp = Z + ((size_t)(b * Nn + mg)) * KC + kgcol + (lane & 15);
      #pragma unroll
      for (int q = 0; q < 4; ++q)
        zp[q * 16] = f2bf(acc[i][q][r] * sc);
    }
  }
}

// ---------------- K4: update GEMM  out = relu(Z @ Wcat + b_self) ----------
// grid (2, 128): ntile, mtile. BM=128, BN=128, BK=64, 4 waves (2x2)
__global__ __launch_bounds__(256) void k_upd(
    const u16* __restrict__ Z, const u16* __restrict__ wcatT,
    const float* __restrict__ bself, float* __restrict__ outp){
  int n0 = blockIdx.x * 128, m0 = blockIdx.y * 128;
  __shared__ u16 As[128 * 72];
  __shared__ u16 Bs[128 * 72];
  int t = threadIdx.x, lane = t & 63, wid = t >> 6;
  int wm = wid >> 1, wn = wid & 1;
  f32x4 acc[4][4];
  #pragma unroll
  for (int i = 0; i < 4; ++i)
    #pragma unroll
    for (int q = 0; q < 4; ++q) acc[i][q] = (f32x4){0.f, 0.f, 0.f, 0.f};

  for (int ks = 0; ks < 28; ++ks){
    int k0 = ks * 64;
    #pragma unroll
    for (int p = 0; p < 4; ++p){
      int row = p * 32 + (t >> 3);
      *(uint4*)&As[row * 72 + (t & 7) * 8] =
          *(const uint4*)(Z + ((size_t)(m0 + row)) * KC + k0 + (t & 7) * 8);
      *(uint4*)&Bs[row * 72 + (t & 7) * 8] =
          *(const uint4*)(wcatT + ((size_t)(n0 + row)) * KC + k0 + (t & 7) * 8);
    }
    __syncthreads();
    #pragma unroll
    for (int kk = 0; kk < 2; ++kk){
      bf16x8 av[4], bv[4];
      #pragma unroll
      for (int i = 0; i < 4; ++i)
        av[i] = *(const bf16x8*)&As[(wm * 64 + i * 16 + (lane & 15)) * 72 + kk * 32 + (lane >> 4) * 8];
      #pragma unroll
      for (int q = 0; q < 4; ++q)
        bv[q] = *(const bf16x8*)&Bs[(wn * 64 + q * 16 + (lane & 15)) * 72 + kk * 32 + (lane >> 4) * 8];
      #pragma unroll
      for (int i = 0; i < 4; ++i)
        #pragma unroll
        for (int q = 0; q < 4; ++q)
          acc[i][q] = __builtin_amdgcn_mfma_f32_16x16x32_bf16(av[i], bv[q], acc[i][q], 0, 0, 0);
    }
    __syncthreads();
  }
  #pragma unroll
  for (int i = 0; i < 4; ++i){
    #pragma unroll
    for (int r = 0; r < 4; ++r){
      int mg = m0 + wm * 64 + i * 16 + (lane >> 4) * 4 + r;
      #pragma unroll
      for (int q = 0; q < 4; ++q){
        int e = n0 + wn * 64 + q * 16 + (lane & 15);
        float v = acc[i][q][r] + bself[e];
        outp[(size_t)mg * Dd + e] = v > 0.f ? v : 0.f;
      }
    }
  }
}

extern "C" void kernel_launch(void* const* d_in, const int* in_sizes, int n_in,
                              void* d_out, int out_size, void* d_ws, size_t ws_size,
                              hipStream_t stream){
  (void)in_sizes; (void)n_in; (void)out_size; (void)ws_size;
  const float* node  = (const float*)d_in[0];
  const int*   mask  = (const int*)d_in[1];
  const int*   g[6];
  for (int i = 0; i < 6; ++i) g[i] = (const int*)d_in[2 + i];
  const float* wnw   = (const float*)d_in[8];
  const float* bnw   = (const float*)d_in[9];
  const float* wself = (const float*)d_in[10];
  const float* bself = (const float*)d_in[11];
  const float* W[6];
  for (int i = 0; i < 6; ++i) W[i] = (const float*)d_in[12 + i];

  float* out_node = (float*)d_out;
  float* out_aw   = out_node + (size_t)Bb * Nn * Dd;

  char* ws = (char*)d_ws;
  u16*      wcatT = (u16*)(ws);                    // 917,504 B
  float*    rs    = (float*)(ws + 917504);         // 65,536 B
  unsigned* Gp    = (unsigned*)(ws + 1048576);     // 6,291,456 B
  u16*      XT    = (u16*)(ws + 7340032);          // 8,388,608 B
  u16*      Z     = (u16*)(ws + 15728640);         // 58,720,256 B -> ends ~71 MB

  k_prep<<<256, 256, 0, stream>>>(wself, W[0], W[1], W[2], W[3], W[4], W[5], wcatT);
  k_pack<<<4096, 256, 0, stream>>>(g[0], g[1], g[2], g[3], g[4], g[5], mask, Gp, rs);

  for (int t = 0; t < 2; ++t){
    const float* nsrc = (t == 0) ? node : out_node;   // iter-1 result lives in d_out
    k_dw<<<512, 256, 0, stream>>>(nsrc, mask, wnw, bnw, out_aw + t * Nn, Z, XT);
    k_agg<<<dim3(8, 32, 6), 256, 0, stream>>>(Gp, XT, rs, Z);
    k_upd<<<dim3(2, 128), 256, 0, stream>>>(Z, wcatT, bself, out_node);
  }
}